// Round 8
// baseline (1829.909 us; speedup 1.0000x reference)
//
#include <hip/hip_runtime.h>
#include <math.h>

#define NN 100000
#define NE 800000
#define NH 128
#define NC 40
#define NB_SCAN 98   // ceil(NN/1024)

typedef __attribute__((ext_vector_type(8))) short short8;
typedef __attribute__((ext_vector_type(4))) float floatx4;
typedef unsigned long long u64;

__device__ __forceinline__ unsigned short f2b(float f) {
  union { float f; unsigned int u; } x; x.f = f;
  unsigned int r = x.u + 0x7fff + ((x.u >> 16) & 1);  // RTNE
  return (unsigned short)(r >> 16);
}
__device__ __forceinline__ float b2f(unsigned int h16) {  // low 16 bits
  union { unsigned int u; float f; } x; x.u = h16 << 16;
  return x.f;
}
__device__ __forceinline__ float4 u2f4(uint2 v) {
  float4 f;
  f.x = b2f(v.x & 0xffff); f.y = b2f(v.x >> 16);
  f.z = b2f(v.y & 0xffff); f.w = b2f(v.y >> 16);
  return f;
}
__device__ __forceinline__ void fma4(float4& a, float s, const float4& w) {
  a.x = fmaf(s, w.x, a.x); a.y = fmaf(s, w.y, a.y);
  a.z = fmaf(s, w.z, a.z); a.w = fmaf(s, w.w, a.w);
}

// ---------------- CSR build ----------------
__global__ void hist_kernel(const int* __restrict__ dst, int* __restrict__ cnt, int E) {
  int i = blockIdx.x * 256 + threadIdx.x;
  if (i < E) atomicAdd(&cnt[dst[i]], 1);
}

__global__ __launch_bounds__(1024) void scan1_kernel(const int* __restrict__ cnt,
                                                     int* __restrict__ rp,
                                                     int* __restrict__ bsum, int n) {
  __shared__ int buf[1024];
  int t = threadIdx.x, i = blockIdx.x * 1024 + t;
  int v = (i < n) ? cnt[i] : 0;
  buf[t] = v;
  __syncthreads();
  for (int off = 1; off < 1024; off <<= 1) {
    int x = (t >= off) ? buf[t - off] : 0;
    __syncthreads();
    buf[t] += x;
    __syncthreads();
  }
  if (i < n) rp[i] = buf[t] - v;
  if (t == 1023) bsum[blockIdx.x] = buf[t];
}

__global__ __launch_bounds__(128) void scan2_kernel(const int* __restrict__ bsum,
                                                    int* __restrict__ boff, int nb) {
  __shared__ int buf[128];
  int t = threadIdx.x;
  int v = (t < nb) ? bsum[t] : 0;
  buf[t] = v;
  __syncthreads();
  for (int off = 1; off < 128; off <<= 1) {
    int x = (t >= off) ? buf[t - off] : 0;
    __syncthreads();
    buf[t] += x;
    __syncthreads();
  }
  if (t < nb) boff[t] = buf[t] - v;
  if (t == 127) boff[nb] = buf[t];
}

// finalize rp and produce the scatter cursor copy in one pass
__global__ void scan3_kernel(int* __restrict__ rp, int* __restrict__ roff,
                             const int* __restrict__ boff, int n, int nb) {
  int i = blockIdx.x * 256 + threadIdx.x;
  if (i < n) {
    int v = rp[i] + boff[i >> 10];
    rp[i] = v;
    roff[i] = v;
  }
  if (i == 0) rp[n] = boff[nb];
}

// edge meta packed: low 32 = src index, high 32 = weight bits
__global__ void scatter_kernel(const int* __restrict__ src, const int* __restrict__ dst,
                               const float* __restrict__ ew, int* __restrict__ off,
                               u64* __restrict__ em, int E) {
  int i = blockIdx.x * 256 + threadIdx.x;
  if (i < E) {
    int p = atomicAdd(&off[dst[i]], 1);
    em[p] = (u64)(unsigned int)src[i] | ((u64)__float_as_uint(ew[i]) << 32);
  }
}

// ---------------- prep: x (fp32 row-major) -> bf16 CHUNKED layout ----------------
// Hc[chunk][node][16 cols], chunk = col>>4: 3.2 MB per-XCD-L2-resident slices
__global__ void xconv_kernel(const float* __restrict__ in, unsigned short* __restrict__ Hc,
                             int n4) {
  int i = blockIdx.x * 256 + threadIdx.x;  // float4 index over [NN,128]
  if (i < n4) {
    float4 v = ((const float4*)in)[i];
    int node = i >> 5;
    int q = i & 31;
    int chunk = q >> 2;
    int within = (q & 3) * 4;
    unsigned short* o = Hc + ((size_t)chunk * NN + node) * 16 + within;
    o[0] = f2b(v.x); o[1] = f2b(v.y); o[2] = f2b(v.z); o[3] = f2b(v.w);
  }
}

// 9 dense-128 weights -> bf16, TRANSPOSED: WT[l][n][k] = W_l[k][n]
__global__ void wconv_kernel(const float* __restrict__ W1, const float* __restrict__ Wh,
                             unsigned short* __restrict__ WT) {
  int idx = blockIdx.x * 256 + threadIdx.x;  // 9*16384
  if (idx >= 9 * 16384) return;
  int l = idx >> 14, r = idx & 16383;
  int k = r >> 7, n = r & 127;
  const float* W = (l == 0) ? W1 : (Wh + (size_t)(l - 1) * 16384);
  WT[(size_t)l * 16384 + n * 128 + k] = f2b(W[r]);
}

// ---------------- spmm gather (chunk-partitioned): Agg = A * Hc ----------------
// grid = 8 chunks x node-groups of 64; chunk = blockIdx&7 (XCD affinity heuristic).
// wave = 16 nodes x 4 lanes; lane owns 4 cols (uint2). Edge meta via nontemporal
// 8B loads (no L2 allocate -> chunk slice stays resident). 4-way unroll.
__global__ __launch_bounds__(256) void spmm_gather_kernel(const unsigned short* __restrict__ Hc,
                                                          const int* __restrict__ rp,
                                                          const u64* __restrict__ em,
                                                          unsigned short* __restrict__ Agg) {
  int chunk = blockIdx.x & 7;
  int ng = blockIdx.x >> 3;
  int wave = threadIdx.x >> 6;
  int lane = threadIdx.x & 63;
  int nsub = lane >> 2;   // 0..15
  int csub = lane & 3;    // 0..3
  int node = ng * 64 + wave * 16 + nsub;
  if (node >= NN) return;
  const uint2* H2 = (const uint2*)Hc + (size_t)chunk * NN * 4 + csub;
  int e0 = rp[node], e1 = rp[node + 1];
  float4 A0 = {0,0,0,0}, A1 = {0,0,0,0}, A2 = {0,0,0,0}, A3 = {0,0,0,0};
  int e = e0;
  for (; e + 4 <= e1; e += 4) {
    u64 m0 = __builtin_nontemporal_load(em + e);
    u64 m1 = __builtin_nontemporal_load(em + e + 1);
    u64 m2 = __builtin_nontemporal_load(em + e + 2);
    u64 m3 = __builtin_nontemporal_load(em + e + 3);
    uint2 v0 = H2[(size_t)(unsigned int)m0 * 4];
    uint2 v1 = H2[(size_t)(unsigned int)m1 * 4];
    uint2 v2 = H2[(size_t)(unsigned int)m2 * 4];
    uint2 v3 = H2[(size_t)(unsigned int)m3 * 4];
    fma4(A0, __uint_as_float((unsigned int)(m0 >> 32)), u2f4(v0));
    fma4(A1, __uint_as_float((unsigned int)(m1 >> 32)), u2f4(v1));
    fma4(A2, __uint_as_float((unsigned int)(m2 >> 32)), u2f4(v2));
    fma4(A3, __uint_as_float((unsigned int)(m3 >> 32)), u2f4(v3));
  }
  for (; e < e1; ++e) {
    u64 me = __builtin_nontemporal_load(em + e);
    uint2 v = H2[(size_t)(unsigned int)me * 4];
    fma4(A0, __uint_as_float((unsigned int)(me >> 32)), u2f4(v));
  }
  float4 r;
  r.x = (A0.x + A1.x) + (A2.x + A3.x);
  r.y = (A0.y + A1.y) + (A2.y + A3.y);
  r.z = (A0.z + A1.z) + (A2.z + A3.z);
  r.w = (A0.w + A1.w) + (A2.w + A3.w);
  // Agg row-major [node][128] bf16 = 32 u64 slots/row; chunk spans 4 slots.
  u64 packed = (u64)((unsigned int)f2b(r.x) | ((unsigned int)f2b(r.y) << 16)) |
               ((u64)((unsigned int)f2b(r.z) | ((unsigned int)f2b(r.w) << 16)) << 32);
  __builtin_nontemporal_store(packed, (u64*)Agg + (size_t)node * 32 + chunk * 4 + csub);
}

// ---------------- fused MFMA layer (LDS-free): Hc_out = bf16(relu(Agg*W+b)[+Hc_prev]) ----------------
// block = 256 thr (4 waves), 128 rows/block; wave owns 64x64 quadrant.
// A fragments: disjoint per-lane global reads. B: 32 KB WT, L2-hot. No LDS/barrier.
__global__ __launch_bounds__(256) void mfma_fused_kernel(const unsigned short* __restrict__ Agg,
                                                         const unsigned short* __restrict__ WT,
                                                         const float* __restrict__ bias,
                                                         const unsigned short* __restrict__ Hprev,
                                                         unsigned short* __restrict__ Hout,
                                                         int residual) {
  int tid = threadIdx.x;
  int row0 = blockIdx.x * 128;
  int wave = tid >> 6;
  int lane = tid & 63;
  int m = lane & 15;
  int quad = lane >> 4;
  int wr0 = (wave >> 1) * 64;
  int wc0 = (wave & 1) * 64;

  floatx4 acc[4][4];
#pragma unroll
  for (int mt = 0; mt < 4; ++mt)
#pragma unroll
    for (int nt = 0; nt < 4; ++nt) acc[mt][nt] = (floatx4){0.f, 0.f, 0.f, 0.f};

  int ga[4];
#pragma unroll
  for (int mt = 0; mt < 4; ++mt) {
    int gr = row0 + wr0 + mt * 16 + m;
    ga[mt] = (gr < NN) ? gr : (NN - 1);
  }

#pragma unroll
  for (int ks = 0; ks < 4; ++ks) {
    short8 a[4], b[4];
#pragma unroll
    for (int mt = 0; mt < 4; ++mt)
      a[mt] = *(const short8*)(Agg + (size_t)ga[mt] * 128 + quad * 8 + ks * 32);
#pragma unroll
    for (int nt = 0; nt < 4; ++nt)
      b[nt] = *(const short8*)(WT + (size_t)(wc0 + nt * 16 + m) * 128 + quad * 8 + ks * 32);
#pragma unroll
    for (int mt = 0; mt < 4; ++mt)
#pragma unroll
      for (int nt = 0; nt < 4; ++nt)
        acc[mt][nt] = __builtin_amdgcn_mfma_f32_16x16x32_bf16(a[mt], b[nt], acc[mt][nt], 0, 0, 0);
  }

  // D: row = quad*4+reg, col = wc0+nt*16+m -> chunk = (wc0>>4)+nt, within = m
  int chunk0 = wc0 >> 4;
#pragma unroll
  for (int nt = 0; nt < 4; ++nt) {
    float bcol = bias[wc0 + nt * 16 + m];
#pragma unroll
    for (int mt = 0; mt < 4; ++mt) {
#pragma unroll
      for (int reg = 0; reg < 4; ++reg) {
        int gr = row0 + wr0 + mt * 16 + quad * 4 + reg;
        if (gr < NN) {
          size_t off = ((size_t)(chunk0 + nt) * NN + gr) * 16 + m;
          float v = fmaxf(acc[mt][nt][reg] + bcol, 0.f);
          if (residual) v += b2f(Hprev[off]);
          Hout[off] = f2b(v);
        }
      }
    }
  }
}

// ---------------- final dense matmul: [NN,128](bf16 Agg) @ [128,40] + bias + relu ----------------
__global__ __launch_bounds__(256) void matmul40_kernel(const unsigned short* __restrict__ Agg,
                                                       const float* __restrict__ W10,
                                                       const float* __restrict__ b10,
                                                       float* __restrict__ S) {
  __shared__ float Wsf[128 * NC + 64];
  __shared__ float Hsf[32 * 128];
  int tid = threadIdx.x;
  size_t row0 = (size_t)blockIdx.x * 32;

  for (int i = tid; i < 128 * NC / 4; i += 256) ((float4*)Wsf)[i] = ((const float4*)W10)[i];
  const uint2* A8 = (const uint2*)(Agg + row0 * NH);
  for (int i = tid; i < 1024; i += 256) ((float4*)Hsf)[i] = u2f4(A8[i]);
  __syncthreads();

  int c = tid & 63;
  int rg = tid >> 6;
  float acc[8];
#pragma unroll
  for (int r = 0; r < 8; ++r) acc[r] = 0.f;

  const float4* Hs4 = (const float4*)Hsf;
  for (int kk = 0; kk < 32; ++kk) {
    float4 hv[8];
#pragma unroll
    for (int r = 0; r < 8; ++r) hv[r] = Hs4[(rg + 4 * r) * 32 + kk];
#pragma unroll
    for (int j = 0; j < 4; ++j) {
      float wv = Wsf[(4 * kk + j) * NC + c];
#pragma unroll
      for (int r = 0; r < 8; ++r) {
        float s = (j == 0) ? hv[r].x : (j == 1) ? hv[r].y : (j == 2) ? hv[r].z : hv[r].w;
        acc[r] = fmaf(s, wv, acc[r]);
      }
    }
  }
  if (c < NC) {
    float bc = b10[c];
#pragma unroll
    for (int r = 0; r < 8; ++r)
      S[(row0 + rg + 4 * r) * NC + c] = fmaxf(acc[r] + bc, 0.f);
  }
}

// ---------------- log_softmax over 40 logits per node ----------------
__global__ __launch_bounds__(256) void lsm_kernel(const float* __restrict__ S,
                                                  float* __restrict__ out) {
  int node = blockIdx.x * 4 + (threadIdx.x >> 6);
  int lane = threadIdx.x & 63;
  if (node >= NN) return;
  float v = (lane < NC) ? S[(size_t)node * NC + lane] : -INFINITY;
  float mx = v;
#pragma unroll
  for (int off = 32; off; off >>= 1) mx = fmaxf(mx, __shfl_xor(mx, off));
  float ex = (lane < NC) ? expf(v - mx) : 0.f;
  float ss = ex;
#pragma unroll
  for (int off = 32; off; off >>= 1) ss += __shfl_xor(ss, off);
  if (lane < NC) out[(size_t)node * NC + lane] = v - mx - logf(ss);
}

extern "C" void kernel_launch(void* const* d_in, const int* in_sizes, int n_in,
                              void* d_out, int out_size, void* d_ws, size_t ws_size,
                              hipStream_t stream) {
  const float* x   = (const float*)d_in[0];
  const int*   src = (const int*)d_in[1];
  const int*   dst = (const int*)d_in[2];
  const float* ew  = (const float*)d_in[3];
  const float* W1  = (const float*)d_in[4];
  const float* Wh  = (const float*)d_in[5];
  const float* W10 = (const float*)d_in[6];
  const float* b1  = (const float*)d_in[7];
  const float* bh  = (const float*)d_in[8];
  const float* b10 = (const float*)d_in[9];
  float* out = (float*)d_out;

  // workspace layout (256B-aligned chunks), ~75 MB
  char* p = (char*)d_ws;
  int*   rp    = (int*)p;            p += (((size_t)(NN + 1) * 4 + 255) / 256) * 256;
  int*   roff  = (int*)p;            p += (((size_t)NN * 4 + 255) / 256) * 256;
  int*   bsum  = (int*)p;            p += 256 * 4;
  int*   boff  = (int*)p;            p += 256 * 4;
  u64*   em    = (u64*)p;            p += (size_t)NE * 8;
  unsigned short* hb   = (unsigned short*)p; p += (size_t)NN * NH * 2;  // chunked
  unsigned short* aggb = (unsigned short*)p; p += (size_t)NN * NH * 2;  // row-major
  float* sup40 = (float*)p;          p += (size_t)NN * NC * 4;
  unsigned short* WT   = (unsigned short*)p; p += (size_t)9 * NH * NH * 2;

  // ---- build CSR ----
  hipMemsetAsync(roff, 0, (size_t)NN * 4, stream);
  hist_kernel<<<(NE + 255) / 256, 256, 0, stream>>>(dst, roff, NE);
  scan1_kernel<<<NB_SCAN, 1024, 0, stream>>>(roff, rp, bsum, NN);
  scan2_kernel<<<1, 128, 0, stream>>>(bsum, boff, NB_SCAN);
  scan3_kernel<<<(NN + 255) / 256, 256, 0, stream>>>(rp, roff, boff, NN, NB_SCAN);
  scatter_kernel<<<(NE + 255) / 256, 256, 0, stream>>>(src, dst, ew, roff, em, NE);

  // ---- prep converts ----
  xconv_kernel<<<(NN * NH / 4 + 255) / 256, 256, 0, stream>>>(x, hb, NN * NH / 4);
  wconv_kernel<<<(9 * 16384 + 255) / 256, 256, 0, stream>>>(W1, Wh, WT);

  int gather_grid = 8 * ((NN + 63) / 64);

  // ---- layer 1: agg = A*x ; h = relu(agg*W1 + b1) ----
  spmm_gather_kernel<<<gather_grid, 256, 0, stream>>>(hb, rp, em, aggb);
  mfma_fused_kernel<<<(NN + 127) / 128, 256, 0, stream>>>(aggb, WT, b1, hb, hb, 0);

  // ---- 8 hidden residual layers ----
  for (int i = 0; i < 8; ++i) {
    spmm_gather_kernel<<<gather_grid, 256, 0, stream>>>(hb, rp, em, aggb);
    mfma_fused_kernel<<<(NN + 127) / 128, 256, 0, stream>>>(
        aggb, WT + (size_t)(i + 1) * NH * NH, bh + (size_t)i * NH, hb, hb, 1);
  }

  // ---- final layer + log_softmax ----
  spmm_gather_kernel<<<gather_grid, 256, 0, stream>>>(hb, rp, em, aggb);
  matmul40_kernel<<<(NN + 31) / 32, 256, 0, stream>>>(aggb, W10, b10, sup40);
  lsm_kernel<<<(NN + 3) / 4, 256, 0, stream>>>(sup40, out);
}

// Round 9
// 1041.870 us; speedup vs baseline: 1.7564x; 1.7564x over previous
//
#include <hip/hip_runtime.h>
#include <math.h>

#define NN 100000
#define NE 800000
#define NH 128
#define NC 40
#define NB_SCAN 98   // ceil(NN/1024)
#define LDH 136      // LDS row stride in shorts (272 B): 16B-aligned, 2-way bank alias only

typedef __attribute__((ext_vector_type(8))) short short8;
typedef __attribute__((ext_vector_type(4))) float floatx4;
typedef unsigned long long u64;

__device__ __forceinline__ unsigned short f2b(float f) {
  union { float f; unsigned int u; } x; x.f = f;
  unsigned int r = x.u + 0x7fff + ((x.u >> 16) & 1);  // RTNE
  return (unsigned short)(r >> 16);
}
__device__ __forceinline__ float b2f(unsigned int h16) {  // low 16 bits
  union { unsigned int u; float f; } x; x.u = h16 << 16;
  return x.f;
}
__device__ __forceinline__ unsigned int pk(float lo, float hi) {
  return (unsigned int)f2b(lo) | ((unsigned int)f2b(hi) << 16);
}
__device__ __forceinline__ void acc8(float* a, float w, uint4 v) {
  a[0] = fmaf(w, b2f(v.x & 0xffff), a[0]); a[1] = fmaf(w, b2f(v.x >> 16), a[1]);
  a[2] = fmaf(w, b2f(v.y & 0xffff), a[2]); a[3] = fmaf(w, b2f(v.y >> 16), a[3]);
  a[4] = fmaf(w, b2f(v.z & 0xffff), a[4]); a[5] = fmaf(w, b2f(v.z >> 16), a[5]);
  a[6] = fmaf(w, b2f(v.w & 0xffff), a[6]); a[7] = fmaf(w, b2f(v.w >> 16), a[7]);
}

// ---------------- CSR build ----------------
__global__ void hist_kernel(const int* __restrict__ dst, int* __restrict__ cnt, int E) {
  int i = blockIdx.x * 256 + threadIdx.x;
  if (i < E) atomicAdd(&cnt[dst[i]], 1);
}

__global__ __launch_bounds__(1024) void scan1_kernel(const int* __restrict__ cnt,
                                                     int* __restrict__ rp,
                                                     int* __restrict__ bsum, int n) {
  __shared__ int buf[1024];
  int t = threadIdx.x, i = blockIdx.x * 1024 + t;
  int v = (i < n) ? cnt[i] : 0;
  buf[t] = v;
  __syncthreads();
  for (int off = 1; off < 1024; off <<= 1) {
    int x = (t >= off) ? buf[t - off] : 0;
    __syncthreads();
    buf[t] += x;
    __syncthreads();
  }
  if (i < n) rp[i] = buf[t] - v;
  if (t == 1023) bsum[blockIdx.x] = buf[t];
}

__global__ __launch_bounds__(128) void scan2_kernel(const int* __restrict__ bsum,
                                                    int* __restrict__ boff, int nb) {
  __shared__ int buf[128];
  int t = threadIdx.x;
  int v = (t < nb) ? bsum[t] : 0;
  buf[t] = v;
  __syncthreads();
  for (int off = 1; off < 128; off <<= 1) {
    int x = (t >= off) ? buf[t - off] : 0;
    __syncthreads();
    buf[t] += x;
    __syncthreads();
  }
  if (t < nb) boff[t] = buf[t] - v;
  if (t == 127) boff[nb] = buf[t];
}

__global__ void scan3_kernel(int* __restrict__ rp, int* __restrict__ roff,
                             const int* __restrict__ boff, int n, int nb) {
  int i = blockIdx.x * 256 + threadIdx.x;
  if (i < n) {
    int v = rp[i] + boff[i >> 10];
    rp[i] = v;
    roff[i] = v;
  }
  if (i == 0) rp[n] = boff[nb];
}

// edge meta packed: low 32 = src index, high 32 = weight bits
__global__ void scatter_kernel(const int* __restrict__ src, const int* __restrict__ dst,
                               const float* __restrict__ ew, int* __restrict__ off,
                               u64* __restrict__ em, int E) {
  int i = blockIdx.x * 256 + threadIdx.x;
  if (i < E) {
    int p = atomicAdd(&off[dst[i]], 1);
    em[p] = (u64)(unsigned int)src[i] | ((u64)__float_as_uint(ew[i]) << 32);
  }
}

// ---------------- prep: x fp32 -> bf16 row-major ----------------
__global__ void xconv_kernel(const float* __restrict__ in, unsigned short* __restrict__ out,
                             int n4) {
  int i = blockIdx.x * 256 + threadIdx.x;
  if (i < n4) {
    float4 v = ((const float4*)in)[i];
    uint2 o; o.x = pk(v.x, v.y); o.y = pk(v.z, v.w);
    ((uint2*)out)[i] = o;
  }
}

// 9 dense-128 weights -> bf16, TRANSPOSED: WT[l][n][k] = W_l[k][n]
__global__ void wconv_kernel(const float* __restrict__ W1, const float* __restrict__ Wh,
                             unsigned short* __restrict__ WT) {
  int idx = blockIdx.x * 256 + threadIdx.x;  // 9*16384
  if (idx >= 9 * 16384) return;
  int l = idx >> 14, r = idx & 16383;
  int k = r >> 7, n = r & 127;
  const float* W = (l == 0) ? W1 : (Wh + (size_t)(l - 1) * 16384);
  WT[(size_t)l * 16384 + n * 128 + k] = f2b(W[r]);
}

// ---------------- fused layer: Hout = bf16(relu((A*Hin)*W + b) [+ Hin]) ----------------
// Phase 1: gather 128 agg rows into LDS (16 lanes/node, uint4 row slices, 2-way unroll).
// Phase 2: 64x64-quadrant MFMA per wave; B-fragments from global WT (L2-hot).
__global__ __launch_bounds__(256, 4) void layer_kernel(const unsigned short* __restrict__ Hin,
                                                       const int* __restrict__ rp,
                                                       const u64* __restrict__ em,
                                                       const unsigned short* __restrict__ WT,
                                                       const float* __restrict__ bias,
                                                       unsigned short* __restrict__ Hout,
                                                       int residual) {
  __shared__ unsigned short Hs[128 * LDH];
  int tid = threadIdx.x;
  int wave = tid >> 6, lane = tid & 63;
  int row0 = blockIdx.x * 128;
  int nsub = lane >> 4;   // 0..3
  int csub = lane & 15;   // 0..15 -> cols csub*8 .. +7
  const uint4* H4 = (const uint4*)Hin;  // 16 uint4 per row

  for (int r = 0; r < 8; ++r) {
    int nl = r * 16 + wave * 4 + nsub;
    int node = row0 + nl;
    float a[8] = {0, 0, 0, 0, 0, 0, 0, 0};
    float b[8] = {0, 0, 0, 0, 0, 0, 0, 0};
    if (node < NN) {
      int e0 = rp[node], e1 = rp[node + 1];
      int e = e0;
      for (; e + 2 <= e1; e += 2) {
        u64 m0 = em[e], m1 = em[e + 1];
        uint4 v0 = H4[(size_t)(unsigned int)m0 * 16 + csub];
        uint4 v1 = H4[(size_t)(unsigned int)m1 * 16 + csub];
        acc8(a, __uint_as_float((unsigned int)(m0 >> 32)), v0);
        acc8(b, __uint_as_float((unsigned int)(m1 >> 32)), v1);
      }
      if (e < e1) {
        u64 m0 = em[e];
        uint4 v0 = H4[(size_t)(unsigned int)m0 * 16 + csub];
        acc8(a, __uint_as_float((unsigned int)(m0 >> 32)), v0);
      }
    }
    uint4 o;
    o.x = pk(a[0] + b[0], a[1] + b[1]);
    o.y = pk(a[2] + b[2], a[3] + b[3]);
    o.z = pk(a[4] + b[4], a[5] + b[5]);
    o.w = pk(a[6] + b[6], a[7] + b[7]);
    *(uint4*)(Hs + nl * LDH + csub * 8) = o;
  }
  __syncthreads();

  int m = lane & 15;
  int quad = lane >> 4;
  int wr0 = (wave >> 1) * 64;
  int wc0 = (wave & 1) * 64;

  floatx4 acc[4][4];
#pragma unroll
  for (int mt = 0; mt < 4; ++mt)
#pragma unroll
    for (int nt = 0; nt < 4; ++nt) acc[mt][nt] = (floatx4){0.f, 0.f, 0.f, 0.f};

#pragma unroll
  for (int ks = 0; ks < 4; ++ks) {
    short8 af[4], bf[4];
#pragma unroll
    for (int mt = 0; mt < 4; ++mt)
      af[mt] = *(const short8*)(Hs + (wr0 + mt * 16 + m) * LDH + quad * 8 + ks * 32);
#pragma unroll
    for (int nt = 0; nt < 4; ++nt)
      bf[nt] = *(const short8*)(WT + (size_t)(wc0 + nt * 16 + m) * 128 + quad * 8 + ks * 32);
#pragma unroll
    for (int mt = 0; mt < 4; ++mt)
#pragma unroll
      for (int nt = 0; nt < 4; ++nt)
        acc[mt][nt] = __builtin_amdgcn_mfma_f32_16x16x32_bf16(af[mt], bf[nt], acc[mt][nt], 0, 0, 0);
  }

  // D: row = quad*4+reg (within 16-tile), col = wc0 + nt*16 + m
#pragma unroll
  for (int nt = 0; nt < 4; ++nt) {
    int col = wc0 + nt * 16 + m;
    float bcol = bias[col];
#pragma unroll
    for (int mt = 0; mt < 4; ++mt) {
#pragma unroll
      for (int reg = 0; reg < 4; ++reg) {
        int gr = row0 + wr0 + mt * 16 + quad * 4 + reg;
        if (gr < NN) {
          float v = fmaxf(acc[mt][nt][reg] + bcol, 0.f);
          if (residual) v += b2f(Hin[(size_t)gr * 128 + col]);
          Hout[(size_t)gr * 128 + col] = f2b(v);
        }
      }
    }
  }
}

// ---------------- standalone gather (final layer): Agg = A * Hin ----------------
__global__ __launch_bounds__(256) void gather_kernel(const unsigned short* __restrict__ Hin,
                                                     const int* __restrict__ rp,
                                                     const u64* __restrict__ em,
                                                     unsigned short* __restrict__ Agg) {
  int tid = threadIdx.x;
  int wave = tid >> 6, lane = tid & 63;
  int nsub = lane >> 4, csub = lane & 15;
  int node = blockIdx.x * 16 + wave * 4 + nsub;
  if (node >= NN) return;
  const uint4* H4 = (const uint4*)Hin;
  int e0 = rp[node], e1 = rp[node + 1];
  float a[8] = {0, 0, 0, 0, 0, 0, 0, 0};
  float b[8] = {0, 0, 0, 0, 0, 0, 0, 0};
  int e = e0;
  for (; e + 2 <= e1; e += 2) {
    u64 m0 = em[e], m1 = em[e + 1];
    uint4 v0 = H4[(size_t)(unsigned int)m0 * 16 + csub];
    uint4 v1 = H4[(size_t)(unsigned int)m1 * 16 + csub];
    acc8(a, __uint_as_float((unsigned int)(m0 >> 32)), v0);
    acc8(b, __uint_as_float((unsigned int)(m1 >> 32)), v1);
  }
  if (e < e1) {
    u64 m0 = em[e];
    uint4 v0 = H4[(size_t)(unsigned int)m0 * 16 + csub];
    acc8(a, __uint_as_float((unsigned int)(m0 >> 32)), v0);
  }
  uint4 o;
  o.x = pk(a[0] + b[0], a[1] + b[1]);
  o.y = pk(a[2] + b[2], a[3] + b[3]);
  o.z = pk(a[4] + b[4], a[5] + b[5]);
  o.w = pk(a[6] + b[6], a[7] + b[7]);
  ((uint4*)Agg)[(size_t)node * 16 + csub] = o;
}

// ---------------- final dense matmul: [NN,128](bf16 Agg) @ [128,40] + bias + relu ----------------
__device__ __forceinline__ float4 u2f4(uint2 v) {
  float4 f;
  f.x = b2f(v.x & 0xffff); f.y = b2f(v.x >> 16);
  f.z = b2f(v.y & 0xffff); f.w = b2f(v.y >> 16);
  return f;
}

__global__ __launch_bounds__(256) void matmul40_kernel(const unsigned short* __restrict__ Agg,
                                                       const float* __restrict__ W10,
                                                       const float* __restrict__ b10,
                                                       float* __restrict__ S) {
  __shared__ float Wsf[128 * NC + 64];
  __shared__ float Hsf[32 * 128];
  int tid = threadIdx.x;
  size_t row0 = (size_t)blockIdx.x * 32;

  for (int i = tid; i < 128 * NC / 4; i += 256) ((float4*)Wsf)[i] = ((const float4*)W10)[i];
  const uint2* A8 = (const uint2*)(Agg + row0 * NH);
  for (int i = tid; i < 1024; i += 256) ((float4*)Hsf)[i] = u2f4(A8[i]);
  __syncthreads();

  int c = tid & 63;
  int rg = tid >> 6;
  float acc[8];
#pragma unroll
  for (int r = 0; r < 8; ++r) acc[r] = 0.f;

  const float4* Hs4 = (const float4*)Hsf;
  for (int kk = 0; kk < 32; ++kk) {
    float4 hv[8];
#pragma unroll
    for (int r = 0; r < 8; ++r) hv[r] = Hs4[(rg + 4 * r) * 32 + kk];
#pragma unroll
    for (int j = 0; j < 4; ++j) {
      float wv = Wsf[(4 * kk + j) * NC + c];
#pragma unroll
      for (int r = 0; r < 8; ++r) {
        float s = (j == 0) ? hv[r].x : (j == 1) ? hv[r].y : (j == 2) ? hv[r].z : hv[r].w;
        acc[r] = fmaf(s, wv, acc[r]);
      }
    }
  }
  if (c < NC) {
    float bc = b10[c];
#pragma unroll
    for (int r = 0; r < 8; ++r)
      S[(row0 + rg + 4 * r) * NC + c] = fmaxf(acc[r] + bc, 0.f);
  }
}

// ---------------- log_softmax over 40 logits per node ----------------
__global__ __launch_bounds__(256) void lsm_kernel(const float* __restrict__ S,
                                                  float* __restrict__ out) {
  int node = blockIdx.x * 4 + (threadIdx.x >> 6);
  int lane = threadIdx.x & 63;
  if (node >= NN) return;
  float v = (lane < NC) ? S[(size_t)node * NC + lane] : -INFINITY;
  float mx = v;
#pragma unroll
  for (int off = 32; off; off >>= 1) mx = fmaxf(mx, __shfl_xor(mx, off));
  float ex = (lane < NC) ? expf(v - mx) : 0.f;
  float ss = ex;
#pragma unroll
  for (int off = 32; off; off >>= 1) ss += __shfl_xor(ss, off);
  if (lane < NC) out[(size_t)node * NC + lane] = v - mx - logf(ss);
}

extern "C" void kernel_launch(void* const* d_in, const int* in_sizes, int n_in,
                              void* d_out, int out_size, void* d_ws, size_t ws_size,
                              hipStream_t stream) {
  const float* x   = (const float*)d_in[0];
  const int*   src = (const int*)d_in[1];
  const int*   dst = (const int*)d_in[2];
  const float* ew  = (const float*)d_in[3];
  const float* W1  = (const float*)d_in[4];
  const float* Wh  = (const float*)d_in[5];
  const float* W10 = (const float*)d_in[6];
  const float* b1  = (const float*)d_in[7];
  const float* bh  = (const float*)d_in[8];
  const float* b10 = (const float*)d_in[9];
  float* out = (float*)d_out;

  // workspace layout (256B-aligned chunks), ~100 MB
  char* p = (char*)d_ws;
  int*   rp    = (int*)p;            p += (((size_t)(NN + 1) * 4 + 255) / 256) * 256;
  int*   roff  = (int*)p;            p += (((size_t)NN * 4 + 255) / 256) * 256;
  int*   bsum  = (int*)p;            p += 256 * 4;
  int*   boff  = (int*)p;            p += 256 * 4;
  u64*   em    = (u64*)p;            p += (size_t)NE * 8;
  unsigned short* hA   = (unsigned short*)p; p += (size_t)NN * NH * 2;
  unsigned short* hB   = (unsigned short*)p; p += (size_t)NN * NH * 2;  // also x-bf16
  unsigned short* aggb = (unsigned short*)p; p += (size_t)NN * NH * 2;
  float* sup40 = (float*)p;          p += (size_t)NN * NC * 4;
  unsigned short* WT   = (unsigned short*)p; p += (size_t)9 * NH * NH * 2;

  // ---- build CSR ----
  hipMemsetAsync(roff, 0, (size_t)NN * 4, stream);
  hist_kernel<<<(NE + 255) / 256, 256, 0, stream>>>(dst, roff, NE);
  scan1_kernel<<<NB_SCAN, 1024, 0, stream>>>(roff, rp, bsum, NN);
  scan2_kernel<<<1, 128, 0, stream>>>(bsum, boff, NB_SCAN);
  scan3_kernel<<<(NN + 255) / 256, 256, 0, stream>>>(rp, roff, boff, NN, NB_SCAN);
  scatter_kernel<<<(NE + 255) / 256, 256, 0, stream>>>(src, dst, ew, roff, em, NE);

  // ---- prep converts ----
  xconv_kernel<<<(NN * NH / 4 + 255) / 256, 256, 0, stream>>>(x, hB, NN * NH / 4);
  wconv_kernel<<<(9 * 16384 + 255) / 256, 256, 0, stream>>>(W1, Wh, WT);

  int layer_grid = (NN + 127) / 128;

  // ---- layer 1: hA = relu((A*x)W1 + b1) ----
  layer_kernel<<<layer_grid, 256, 0, stream>>>(hB, rp, em, WT, b1, hA, 0);

  // ---- 8 hidden residual layers (ping-pong hA/hB) ----
  unsigned short* cur = hA;
  unsigned short* nxt = hB;
  for (int i = 0; i < 8; ++i) {
    layer_kernel<<<layer_grid, 256, 0, stream>>>(
        cur, rp, em, WT + (size_t)(i + 1) * NH * NH, bh + (size_t)i * NH, nxt, 1);
    unsigned short* t = cur; cur = nxt; nxt = t;
  }
  // after 8 swaps, cur == hA

  // ---- final layer + log_softmax ----
  gather_kernel<<<(NN + 15) / 16, 256, 0, stream>>>(cur, rp, em, aggb);
  matmul40_kernel<<<NN / 32, 256, 0, stream>>>(aggb, W10, b10, sup40);
  lsm_kernel<<<(NN + 3) / 4, 256, 0, stream>>>(sup40, out);
}

// Round 10
// 1041.531 us; speedup vs baseline: 1.7569x; 1.0003x over previous
//
#include <hip/hip_runtime.h>
#include <math.h>

#define NN 100000
#define NE 800000
#define NH 128
#define NC 40
#define NB_SCAN 98   // ceil(NN/1024)
#define LDH 136      // LDS row stride in shorts (272 B): 16B-aligned, 2-way bank alias only

typedef __attribute__((ext_vector_type(8))) short short8;
typedef __attribute__((ext_vector_type(4))) float floatx4;
typedef unsigned long long u64;

__device__ __forceinline__ unsigned short f2b(float f) {
  union { float f; unsigned int u; } x; x.f = f;
  unsigned int r = x.u + 0x7fff + ((x.u >> 16) & 1);  // RTNE
  return (unsigned short)(r >> 16);
}
__device__ __forceinline__ float b2f(unsigned int h16) {  // low 16 bits
  union { unsigned int u; float f; } x; x.u = h16 << 16;
  return x.f;
}
__device__ __forceinline__ unsigned int pk(float lo, float hi) {
  return (unsigned int)f2b(lo) | ((unsigned int)f2b(hi) << 16);
}
__device__ __forceinline__ void acc8(float* a, float w, uint4 v) {
  a[0] = fmaf(w, b2f(v.x & 0xffff), a[0]); a[1] = fmaf(w, b2f(v.x >> 16), a[1]);
  a[2] = fmaf(w, b2f(v.y & 0xffff), a[2]); a[3] = fmaf(w, b2f(v.y >> 16), a[3]);
  a[4] = fmaf(w, b2f(v.z & 0xffff), a[4]); a[5] = fmaf(w, b2f(v.z >> 16), a[5]);
  a[6] = fmaf(w, b2f(v.w & 0xffff), a[6]); a[7] = fmaf(w, b2f(v.w >> 16), a[7]);
}

// ---------------- CSR build ----------------
__global__ void hist_kernel(const int* __restrict__ dst, int* __restrict__ cnt, int E) {
  int i = blockIdx.x * 256 + threadIdx.x;
  if (i < E) atomicAdd(&cnt[dst[i]], 1);
}

__global__ __launch_bounds__(1024) void scan1_kernel(const int* __restrict__ cnt,
                                                     int* __restrict__ rp,
                                                     int* __restrict__ bsum, int n) {
  __shared__ int buf[1024];
  int t = threadIdx.x, i = blockIdx.x * 1024 + t;
  int v = (i < n) ? cnt[i] : 0;
  buf[t] = v;
  __syncthreads();
  for (int off = 1; off < 1024; off <<= 1) {
    int x = (t >= off) ? buf[t - off] : 0;
    __syncthreads();
    buf[t] += x;
    __syncthreads();
  }
  if (i < n) rp[i] = buf[t] - v;
  if (t == 1023) bsum[blockIdx.x] = buf[t];
}

__global__ __launch_bounds__(128) void scan2_kernel(const int* __restrict__ bsum,
                                                    int* __restrict__ boff, int nb) {
  __shared__ int buf[128];
  int t = threadIdx.x;
  int v = (t < nb) ? bsum[t] : 0;
  buf[t] = v;
  __syncthreads();
  for (int off = 1; off < 128; off <<= 1) {
    int x = (t >= off) ? buf[t - off] : 0;
    __syncthreads();
    buf[t] += x;
    __syncthreads();
  }
  if (t < nb) boff[t] = buf[t] - v;
  if (t == 127) boff[nb] = buf[t];
}

__global__ void scan3_kernel(int* __restrict__ rp, int* __restrict__ roff,
                             const int* __restrict__ boff, int n, int nb) {
  int i = blockIdx.x * 256 + threadIdx.x;
  if (i < n) {
    int v = rp[i] + boff[i >> 10];
    rp[i] = v;
    roff[i] = v;
  }
  if (i == 0) rp[n] = boff[nb];
}

// edge meta packed: low 32 = src index, high 32 = weight bits
__global__ void scatter_kernel(const int* __restrict__ src, const int* __restrict__ dst,
                               const float* __restrict__ ew, int* __restrict__ off,
                               u64* __restrict__ em, int E) {
  int i = blockIdx.x * 256 + threadIdx.x;
  if (i < E) {
    int p = atomicAdd(&off[dst[i]], 1);
    em[p] = (u64)(unsigned int)src[i] | ((u64)__float_as_uint(ew[i]) << 32);
  }
}

// ---------------- prep: x fp32 -> bf16 row-major ----------------
__global__ void xconv_kernel(const float* __restrict__ in, unsigned short* __restrict__ out,
                             int n4) {
  int i = blockIdx.x * 256 + threadIdx.x;
  if (i < n4) {
    float4 v = ((const float4*)in)[i];
    uint2 o; o.x = pk(v.x, v.y); o.y = pk(v.z, v.w);
    ((uint2*)out)[i] = o;
  }
}

// 9 dense-128 weights -> bf16, TRANSPOSED: WT[l][n][k] = W_l[k][n]
__global__ void wconv_kernel(const float* __restrict__ W1, const float* __restrict__ Wh,
                             unsigned short* __restrict__ WT) {
  int idx = blockIdx.x * 256 + threadIdx.x;  // 9*16384
  if (idx >= 9 * 16384) return;
  int l = idx >> 14, r = idx & 16383;
  int k = r >> 7, n = r & 127;
  const float* W = (l == 0) ? W1 : (Wh + (size_t)(l - 1) * 16384);
  WT[(size_t)l * 16384 + n * 128 + k] = f2b(W[r]);
}

// ---------------- fused layer: Hout = bf16(relu((A*Hin)*W + b) [+ Hin]) ----------------
// 64 rows/block (grid 1563 -> ~6 blocks/CU): occupancy-limited gather wants waves.
// Phase 1: gather 64 agg rows into LDS (16 lanes/node, uint4 slices, 2-way unroll).
// Phase 2: 32x64-quadrant MFMA per wave; B-fragments from global WT (L2-hot).
__global__ __launch_bounds__(256, 4) void layer_kernel(const unsigned short* __restrict__ Hin,
                                                       const int* __restrict__ rp,
                                                       const u64* __restrict__ em,
                                                       const unsigned short* __restrict__ WT,
                                                       const float* __restrict__ bias,
                                                       unsigned short* __restrict__ Hout,
                                                       int residual) {
  __shared__ unsigned short Hs[64 * LDH];
  int tid = threadIdx.x;
  int wave = tid >> 6, lane = tid & 63;
  int row0 = blockIdx.x * 64;
  int nsub = lane >> 4;   // 0..3
  int csub = lane & 15;   // 0..15 -> cols csub*8 .. +7
  const uint4* H4 = (const uint4*)Hin;  // 16 uint4 per row

  for (int r = 0; r < 4; ++r) {
    int nl = r * 16 + wave * 4 + nsub;
    int node = row0 + nl;
    float a[8] = {0, 0, 0, 0, 0, 0, 0, 0};
    float b[8] = {0, 0, 0, 0, 0, 0, 0, 0};
    if (node < NN) {
      int e0 = rp[node], e1 = rp[node + 1];
      int e = e0;
      for (; e + 2 <= e1; e += 2) {
        u64 m0 = em[e], m1 = em[e + 1];
        uint4 v0 = H4[(size_t)(unsigned int)m0 * 16 + csub];
        uint4 v1 = H4[(size_t)(unsigned int)m1 * 16 + csub];
        acc8(a, __uint_as_float((unsigned int)(m0 >> 32)), v0);
        acc8(b, __uint_as_float((unsigned int)(m1 >> 32)), v1);
      }
      if (e < e1) {
        u64 m0 = em[e];
        uint4 v0 = H4[(size_t)(unsigned int)m0 * 16 + csub];
        acc8(a, __uint_as_float((unsigned int)(m0 >> 32)), v0);
      }
    }
    uint4 o;
    o.x = pk(a[0] + b[0], a[1] + b[1]);
    o.y = pk(a[2] + b[2], a[3] + b[3]);
    o.z = pk(a[4] + b[4], a[5] + b[5]);
    o.w = pk(a[6] + b[6], a[7] + b[7]);
    *(uint4*)(Hs + nl * LDH + csub * 8) = o;
  }
  __syncthreads();

  int m = lane & 15;
  int quad = lane >> 4;
  int wr0 = (wave >> 1) * 32;   // 2 m-tiles per wave
  int wc0 = (wave & 1) * 64;    // 4 n-tiles per wave

  floatx4 acc[2][4];
#pragma unroll
  for (int mt = 0; mt < 2; ++mt)
#pragma unroll
    for (int nt = 0; nt < 4; ++nt) acc[mt][nt] = (floatx4){0.f, 0.f, 0.f, 0.f};

#pragma unroll
  for (int ks = 0; ks < 4; ++ks) {
    short8 af[2], bf[4];
#pragma unroll
    for (int mt = 0; mt < 2; ++mt)
      af[mt] = *(const short8*)(Hs + (wr0 + mt * 16 + m) * LDH + quad * 8 + ks * 32);
#pragma unroll
    for (int nt = 0; nt < 4; ++nt)
      bf[nt] = *(const short8*)(WT + (size_t)(wc0 + nt * 16 + m) * 128 + quad * 8 + ks * 32);
#pragma unroll
    for (int mt = 0; mt < 2; ++mt)
#pragma unroll
      for (int nt = 0; nt < 4; ++nt)
        acc[mt][nt] = __builtin_amdgcn_mfma_f32_16x16x32_bf16(af[mt], bf[nt], acc[mt][nt], 0, 0, 0);
  }

  // D: row = quad*4+reg (within 16-tile), col = wc0 + nt*16 + m
#pragma unroll
  for (int nt = 0; nt < 4; ++nt) {
    int col = wc0 + nt * 16 + m;
    float bcol = bias[col];
#pragma unroll
    for (int mt = 0; mt < 2; ++mt) {
#pragma unroll
      for (int reg = 0; reg < 4; ++reg) {
        int gr = row0 + wr0 + mt * 16 + quad * 4 + reg;
        if (gr < NN) {
          float v = fmaxf(acc[mt][nt][reg] + bcol, 0.f);
          if (residual) v += b2f(Hin[(size_t)gr * 128 + col]);
          Hout[(size_t)gr * 128 + col] = f2b(v);
        }
      }
    }
  }
}

// ---------------- standalone gather (final layer): Agg = A * Hin ----------------
__global__ __launch_bounds__(256) void gather_kernel(const unsigned short* __restrict__ Hin,
                                                     const int* __restrict__ rp,
                                                     const u64* __restrict__ em,
                                                     unsigned short* __restrict__ Agg) {
  int tid = threadIdx.x;
  int wave = tid >> 6, lane = tid & 63;
  int nsub = lane >> 4, csub = lane & 15;
  int node = blockIdx.x * 16 + wave * 4 + nsub;
  if (node >= NN) return;
  const uint4* H4 = (const uint4*)Hin;
  int e0 = rp[node], e1 = rp[node + 1];
  float a[8] = {0, 0, 0, 0, 0, 0, 0, 0};
  float b[8] = {0, 0, 0, 0, 0, 0, 0, 0};
  int e = e0;
  for (; e + 2 <= e1; e += 2) {
    u64 m0 = em[e], m1 = em[e + 1];
    uint4 v0 = H4[(size_t)(unsigned int)m0 * 16 + csub];
    uint4 v1 = H4[(size_t)(unsigned int)m1 * 16 + csub];
    acc8(a, __uint_as_float((unsigned int)(m0 >> 32)), v0);
    acc8(b, __uint_as_float((unsigned int)(m1 >> 32)), v1);
  }
  if (e < e1) {
    u64 m0 = em[e];
    uint4 v0 = H4[(size_t)(unsigned int)m0 * 16 + csub];
    acc8(a, __uint_as_float((unsigned int)(m0 >> 32)), v0);
  }
  uint4 o;
  o.x = pk(a[0] + b[0], a[1] + b[1]);
  o.y = pk(a[2] + b[2], a[3] + b[3]);
  o.z = pk(a[4] + b[4], a[5] + b[5]);
  o.w = pk(a[6] + b[6], a[7] + b[7]);
  ((uint4*)Agg)[(size_t)node * 16 + csub] = o;
}

// ---------------- final dense matmul: [NN,128](bf16 Agg) @ [128,40] + bias + relu ----------------
__device__ __forceinline__ float4 u2f4(uint2 v) {
  float4 f;
  f.x = b2f(v.x & 0xffff); f.y = b2f(v.x >> 16);
  f.z = b2f(v.y & 0xffff); f.w = b2f(v.y >> 16);
  return f;
}

__global__ __launch_bounds__(256) void matmul40_kernel(const unsigned short* __restrict__ Agg,
                                                       const float* __restrict__ W10,
                                                       const float* __restrict__ b10,
                                                       float* __restrict__ S) {
  __shared__ float Wsf[128 * NC + 64];
  __shared__ float Hsf[32 * 128];
  int tid = threadIdx.x;
  size_t row0 = (size_t)blockIdx.x * 32;

  for (int i = tid; i < 128 * NC / 4; i += 256) ((float4*)Wsf)[i] = ((const float4*)W10)[i];
  const uint2* A8 = (const uint2*)(Agg + row0 * NH);
  for (int i = tid; i < 1024; i += 256) ((float4*)Hsf)[i] = u2f4(A8[i]);
  __syncthreads();

  int c = tid & 63;
  int rg = tid >> 6;
  float acc[8];
#pragma unroll
  for (int r = 0; r < 8; ++r) acc[r] = 0.f;

  const float4* Hs4 = (const float4*)Hsf;
  for (int kk = 0; kk < 32; ++kk) {
    float4 hv[8];
#pragma unroll
    for (int r = 0; r < 8; ++r) hv[r] = Hs4[(rg + 4 * r) * 32 + kk];
#pragma unroll
    for (int j = 0; j < 4; ++j) {
      float wv = Wsf[(4 * kk + j) * NC + c];
#pragma unroll
      for (int r = 0; r < 8; ++r) {
        float s = (j == 0) ? hv[r].x : (j == 1) ? hv[r].y : (j == 2) ? hv[r].z : hv[r].w;
        acc[r] = fmaf(s, wv, acc[r]);
      }
    }
  }
  if (c < NC) {
    float bc = b10[c];
#pragma unroll
    for (int r = 0; r < 8; ++r)
      S[(row0 + rg + 4 * r) * NC + c] = fmaxf(acc[r] + bc, 0.f);
  }
}

// ---------------- log_softmax over 40 logits per node ----------------
__global__ __launch_bounds__(256) void lsm_kernel(const float* __restrict__ S,
                                                  float* __restrict__ out) {
  int node = blockIdx.x * 4 + (threadIdx.x >> 6);
  int lane = threadIdx.x & 63;
  if (node >= NN) return;
  float v = (lane < NC) ? S[(size_t)node * NC + lane] : -INFINITY;
  float mx = v;
#pragma unroll
  for (int off = 32; off; off >>= 1) mx = fmaxf(mx, __shfl_xor(mx, off));
  float ex = (lane < NC) ? expf(v - mx) : 0.f;
  float ss = ex;
#pragma unroll
  for (int off = 32; off; off >>= 1) ss += __shfl_xor(ss, off);
  if (lane < NC) out[(size_t)node * NC + lane] = v - mx - logf(ss);
}

extern "C" void kernel_launch(void* const* d_in, const int* in_sizes, int n_in,
                              void* d_out, int out_size, void* d_ws, size_t ws_size,
                              hipStream_t stream) {
  const float* x   = (const float*)d_in[0];
  const int*   src = (const int*)d_in[1];
  const int*   dst = (const int*)d_in[2];
  const float* ew  = (const float*)d_in[3];
  const float* W1  = (const float*)d_in[4];
  const float* Wh  = (const float*)d_in[5];
  const float* W10 = (const float*)d_in[6];
  const float* b1  = (const float*)d_in[7];
  const float* bh  = (const float*)d_in[8];
  const float* b10 = (const float*)d_in[9];
  float* out = (float*)d_out;

  // workspace layout (256B-aligned chunks), ~100 MB
  char* p = (char*)d_ws;
  int*   rp    = (int*)p;            p += (((size_t)(NN + 1) * 4 + 255) / 256) * 256;
  int*   roff  = (int*)p;            p += (((size_t)NN * 4 + 255) / 256) * 256;
  int*   bsum  = (int*)p;            p += 256 * 4;
  int*   boff  = (int*)p;            p += 256 * 4;
  u64*   em    = (u64*)p;            p += (size_t)NE * 8;
  unsigned short* hA   = (unsigned short*)p; p += (size_t)NN * NH * 2;
  unsigned short* hB   = (unsigned short*)p; p += (size_t)NN * NH * 2;  // also x-bf16
  unsigned short* aggb = (unsigned short*)p; p += (size_t)NN * NH * 2;
  float* sup40 = (float*)p;          p += (size_t)NN * NC * 4;
  unsigned short* WT   = (unsigned short*)p; p += (size_t)9 * NH * NH * 2;

  // ---- build CSR ----
  hipMemsetAsync(roff, 0, (size_t)NN * 4, stream);
  hist_kernel<<<(NE + 255) / 256, 256, 0, stream>>>(dst, roff, NE);
  scan1_kernel<<<NB_SCAN, 1024, 0, stream>>>(roff, rp, bsum, NN);
  scan2_kernel<<<1, 128, 0, stream>>>(bsum, boff, NB_SCAN);
  scan3_kernel<<<(NN + 255) / 256, 256, 0, stream>>>(rp, roff, boff, NN, NB_SCAN);
  scatter_kernel<<<(NE + 255) / 256, 256, 0, stream>>>(src, dst, ew, roff, em, NE);

  // ---- prep converts ----
  xconv_kernel<<<(NN * NH / 4 + 255) / 256, 256, 0, stream>>>(x, hB, NN * NH / 4);
  wconv_kernel<<<(9 * 16384 + 255) / 256, 256, 0, stream>>>(W1, Wh, WT);

  int layer_grid = (NN + 63) / 64;

  // ---- layer 1: hA = relu((A*x)W1 + b1) ----
  layer_kernel<<<layer_grid, 256, 0, stream>>>(hB, rp, em, WT, b1, hA, 0);

  // ---- 8 hidden residual layers (ping-pong hA/hB) ----
  unsigned short* cur = hA;
  unsigned short* nxt = hB;
  for (int i = 0; i < 8; ++i) {
    layer_kernel<<<layer_grid, 256, 0, stream>>>(
        cur, rp, em, WT + (size_t)(i + 1) * NH * NH, bh + (size_t)i * NH, nxt, 1);
    unsigned short* t = cur; cur = nxt; nxt = t;
  }
  // after 8 swaps, cur == hA

  // ---- final layer + log_softmax ----
  gather_kernel<<<(NN + 15) / 16, 256, 0, stream>>>(cur, rp, em, aggb);
  matmul40_kernel<<<NN / 32, 256, 0, stream>>>(aggb, W10, b10, sup40);
  lsm_kernel<<<(NN + 3) / 4, 256, 0, stream>>>(sup40, out);
}

// Round 11
// 1036.813 us; speedup vs baseline: 1.7649x; 1.0045x over previous
//
#include <hip/hip_runtime.h>
#include <math.h>

#define NN 100000
#define NE 800000
#define NH 128
#define NC 40
#define NB_SCAN 98   // ceil(NN/1024)
#define LDH 136      // LDS row stride in shorts (272 B): 16B-aligned, 2-way bank alias only

typedef __attribute__((ext_vector_type(8))) short short8;
typedef __attribute__((ext_vector_type(4))) float floatx4;
typedef unsigned long long u64;

__device__ __forceinline__ unsigned short f2b(float f) {
  union { float f; unsigned int u; } x; x.f = f;
  unsigned int r = x.u + 0x7fff + ((x.u >> 16) & 1);  // RTNE
  return (unsigned short)(r >> 16);
}
__device__ __forceinline__ float b2f(unsigned int h16) {  // low 16 bits
  union { unsigned int u; float f; } x; x.u = h16 << 16;
  return x.f;
}
__device__ __forceinline__ unsigned int pk(float lo, float hi) {
  return (unsigned int)f2b(lo) | ((unsigned int)f2b(hi) << 16);
}
__device__ __forceinline__ void acc8(float* a, float w, uint4 v) {
  a[0] = fmaf(w, b2f(v.x & 0xffff), a[0]); a[1] = fmaf(w, b2f(v.x >> 16), a[1]);
  a[2] = fmaf(w, b2f(v.y & 0xffff), a[2]); a[3] = fmaf(w, b2f(v.y >> 16), a[3]);
  a[4] = fmaf(w, b2f(v.z & 0xffff), a[4]); a[5] = fmaf(w, b2f(v.z >> 16), a[5]);
  a[6] = fmaf(w, b2f(v.w & 0xffff), a[6]); a[7] = fmaf(w, b2f(v.w >> 16), a[7]);
}

// gather 8 bf16 cols of one node's aggregation with 4 independent chains
__device__ __forceinline__ void gather_node(const uint4* __restrict__ H4,
                                            const u64* __restrict__ em,
                                            int e0, int e1, int csub, float* a) {
  float c1[8] = {0,0,0,0,0,0,0,0};
  float c2[8] = {0,0,0,0,0,0,0,0};
  float c3[8] = {0,0,0,0,0,0,0,0};
  int e = e0;
  for (; e + 4 <= e1; e += 4) {
    u64 m0 = em[e], m1 = em[e + 1], m2 = em[e + 2], m3 = em[e + 3];
    uint4 v0 = H4[(size_t)(unsigned int)m0 * 16 + csub];
    uint4 v1 = H4[(size_t)(unsigned int)m1 * 16 + csub];
    uint4 v2 = H4[(size_t)(unsigned int)m2 * 16 + csub];
    uint4 v3 = H4[(size_t)(unsigned int)m3 * 16 + csub];
    acc8(a,  __uint_as_float((unsigned int)(m0 >> 32)), v0);
    acc8(c1, __uint_as_float((unsigned int)(m1 >> 32)), v1);
    acc8(c2, __uint_as_float((unsigned int)(m2 >> 32)), v2);
    acc8(c3, __uint_as_float((unsigned int)(m3 >> 32)), v3);
  }
  for (; e < e1; ++e) {
    u64 m0 = em[e];
    uint4 v0 = H4[(size_t)(unsigned int)m0 * 16 + csub];
    acc8(a, __uint_as_float((unsigned int)(m0 >> 32)), v0);
  }
#pragma unroll
  for (int i = 0; i < 8; ++i) a[i] = (a[i] + c1[i]) + (c2[i] + c3[i]);
}

// ---------------- CSR build ----------------
__global__ void hist_kernel(const int* __restrict__ dst, int* __restrict__ cnt, int E) {
  int i = blockIdx.x * 256 + threadIdx.x;
  if (i < E) atomicAdd(&cnt[dst[i]], 1);
}

__global__ __launch_bounds__(1024) void scan1_kernel(const int* __restrict__ cnt,
                                                     int* __restrict__ rp,
                                                     int* __restrict__ bsum, int n) {
  __shared__ int buf[1024];
  int t = threadIdx.x, i = blockIdx.x * 1024 + t;
  int v = (i < n) ? cnt[i] : 0;
  buf[t] = v;
  __syncthreads();
  for (int off = 1; off < 1024; off <<= 1) {
    int x = (t >= off) ? buf[t - off] : 0;
    __syncthreads();
    buf[t] += x;
    __syncthreads();
  }
  if (i < n) rp[i] = buf[t] - v;
  if (t == 1023) bsum[blockIdx.x] = buf[t];
}

__global__ __launch_bounds__(128) void scan2_kernel(const int* __restrict__ bsum,
                                                    int* __restrict__ boff, int nb) {
  __shared__ int buf[128];
  int t = threadIdx.x;
  int v = (t < nb) ? bsum[t] : 0;
  buf[t] = v;
  __syncthreads();
  for (int off = 1; off < 128; off <<= 1) {
    int x = (t >= off) ? buf[t - off] : 0;
    __syncthreads();
    buf[t] += x;
    __syncthreads();
  }
  if (t < nb) boff[t] = buf[t] - v;
  if (t == 127) boff[nb] = buf[t];
}

__global__ void scan3_kernel(int* __restrict__ rp, int* __restrict__ roff,
                             const int* __restrict__ boff, int n, int nb) {
  int i = blockIdx.x * 256 + threadIdx.x;
  if (i < n) {
    int v = rp[i] + boff[i >> 10];
    rp[i] = v;
    roff[i] = v;
  }
  if (i == 0) rp[n] = boff[nb];
}

// edge meta packed: low 32 = src index, high 32 = weight bits
__global__ void scatter_kernel(const int* __restrict__ src, const int* __restrict__ dst,
                               const float* __restrict__ ew, int* __restrict__ off,
                               u64* __restrict__ em, int E) {
  int i = blockIdx.x * 256 + threadIdx.x;
  if (i < E) {
    int p = atomicAdd(&off[dst[i]], 1);
    em[p] = (u64)(unsigned int)src[i] | ((u64)__float_as_uint(ew[i]) << 32);
  }
}

// ---------------- prep: x fp32 -> bf16 row-major ----------------
__global__ void xconv_kernel(const float* __restrict__ in, unsigned short* __restrict__ out,
                             int n4) {
  int i = blockIdx.x * 256 + threadIdx.x;
  if (i < n4) {
    float4 v = ((const float4*)in)[i];
    uint2 o; o.x = pk(v.x, v.y); o.y = pk(v.z, v.w);
    ((uint2*)out)[i] = o;
  }
}

// 9 dense-128 weights -> bf16, TRANSPOSED: WT[l][n][k] = W_l[k][n]
__global__ void wconv_kernel(const float* __restrict__ W1, const float* __restrict__ Wh,
                             unsigned short* __restrict__ WT) {
  int idx = blockIdx.x * 256 + threadIdx.x;  // 9*16384
  if (idx >= 9 * 16384) return;
  int l = idx >> 14, r = idx & 16383;
  int k = r >> 7, n = r & 127;
  const float* W = (l == 0) ? W1 : (Wh + (size_t)(l - 1) * 16384);
  WT[(size_t)l * 16384 + n * 128 + k] = f2b(W[r]);
}

// ---------------- fused layer: Hout = bf16(relu((A*Hin)*W + b) [+ Hin]) ----------------
// 64 rows/block. Phase 1: gather into LDS (16 lanes/node, 4-chain unroll -> 16
// independent row-gathers in flight per wave). Phase 2: 32x64 MFMA quadrant/wave.
__global__ __launch_bounds__(256, 4) void layer_kernel(const unsigned short* __restrict__ Hin,
                                                       const int* __restrict__ rp,
                                                       const u64* __restrict__ em,
                                                       const unsigned short* __restrict__ WT,
                                                       const float* __restrict__ bias,
                                                       unsigned short* __restrict__ Hout,
                                                       int residual) {
  __shared__ unsigned short Hs[64 * LDH];
  int tid = threadIdx.x;
  int wave = tid >> 6, lane = tid & 63;
  int row0 = blockIdx.x * 64;
  int nsub = lane >> 4;   // 0..3
  int csub = lane & 15;   // 0..15 -> cols csub*8 .. +7
  const uint4* H4 = (const uint4*)Hin;  // 16 uint4 per row

  for (int r = 0; r < 4; ++r) {
    int nl = r * 16 + wave * 4 + nsub;
    int node = row0 + nl;
    float a[8] = {0,0,0,0,0,0,0,0};
    if (node < NN) {
      int e0 = rp[node], e1 = rp[node + 1];
      gather_node(H4, em, e0, e1, csub, a);
    }
    uint4 o;
    o.x = pk(a[0], a[1]);
    o.y = pk(a[2], a[3]);
    o.z = pk(a[4], a[5]);
    o.w = pk(a[6], a[7]);
    *(uint4*)(Hs + nl * LDH + csub * 8) = o;
  }
  __syncthreads();

  int m = lane & 15;
  int quad = lane >> 4;
  int wr0 = (wave >> 1) * 32;   // 2 m-tiles per wave
  int wc0 = (wave & 1) * 64;    // 4 n-tiles per wave

  floatx4 acc[2][4];
#pragma unroll
  for (int mt = 0; mt < 2; ++mt)
#pragma unroll
    for (int nt = 0; nt < 4; ++nt) acc[mt][nt] = (floatx4){0.f, 0.f, 0.f, 0.f};

#pragma unroll
  for (int ks = 0; ks < 4; ++ks) {
    short8 af[2], bf[4];
#pragma unroll
    for (int mt = 0; mt < 2; ++mt)
      af[mt] = *(const short8*)(Hs + (wr0 + mt * 16 + m) * LDH + quad * 8 + ks * 32);
#pragma unroll
    for (int nt = 0; nt < 4; ++nt)
      bf[nt] = *(const short8*)(WT + (size_t)(wc0 + nt * 16 + m) * 128 + quad * 8 + ks * 32);
#pragma unroll
    for (int mt = 0; mt < 2; ++mt)
#pragma unroll
      for (int nt = 0; nt < 4; ++nt)
        acc[mt][nt] = __builtin_amdgcn_mfma_f32_16x16x32_bf16(af[mt], bf[nt], acc[mt][nt], 0, 0, 0);
  }

  // D: row = quad*4+reg (within 16-tile), col = wc0 + nt*16 + m
#pragma unroll
  for (int nt = 0; nt < 4; ++nt) {
    int col = wc0 + nt * 16 + m;
    float bcol = bias[col];
#pragma unroll
    for (int mt = 0; mt < 2; ++mt) {
#pragma unroll
      for (int reg = 0; reg < 4; ++reg) {
        int gr = row0 + wr0 + mt * 16 + quad * 4 + reg;
        if (gr < NN) {
          float v = fmaxf(acc[mt][nt][reg] + bcol, 0.f);
          if (residual) v += b2f(Hin[(size_t)gr * 128 + col]);
          Hout[(size_t)gr * 128 + col] = f2b(v);
        }
      }
    }
  }
}

// ---------------- standalone gather (final layer): Agg = A * Hin ----------------
__global__ __launch_bounds__(256) void gather_kernel(const unsigned short* __restrict__ Hin,
                                                     const int* __restrict__ rp,
                                                     const u64* __restrict__ em,
                                                     unsigned short* __restrict__ Agg) {
  int tid = threadIdx.x;
  int wave = tid >> 6, lane = tid & 63;
  int nsub = lane >> 4, csub = lane & 15;
  int node = blockIdx.x * 16 + wave * 4 + nsub;
  if (node >= NN) return;
  const uint4* H4 = (const uint4*)Hin;
  int e0 = rp[node], e1 = rp[node + 1];
  float a[8] = {0,0,0,0,0,0,0,0};
  gather_node(H4, em, e0, e1, csub, a);
  uint4 o;
  o.x = pk(a[0], a[1]);
  o.y = pk(a[2], a[3]);
  o.z = pk(a[4], a[5]);
  o.w = pk(a[6], a[7]);
  ((uint4*)Agg)[(size_t)node * 16 + csub] = o;
}

// ---------------- final dense matmul: [NN,128](bf16 Agg) @ [128,40] + bias + relu ----------------
__device__ __forceinline__ float4 u2f4(uint2 v) {
  float4 f;
  f.x = b2f(v.x & 0xffff); f.y = b2f(v.x >> 16);
  f.z = b2f(v.y & 0xffff); f.w = b2f(v.y >> 16);
  return f;
}

__global__ __launch_bounds__(256) void matmul40_kernel(const unsigned short* __restrict__ Agg,
                                                       const float* __restrict__ W10,
                                                       const float* __restrict__ b10,
                                                       float* __restrict__ S) {
  __shared__ float Wsf[128 * NC + 64];
  __shared__ float Hsf[32 * 128];
  int tid = threadIdx.x;
  size_t row0 = (size_t)blockIdx.x * 32;

  for (int i = tid; i < 128 * NC / 4; i += 256) ((float4*)Wsf)[i] = ((const float4*)W10)[i];
  const uint2* A8 = (const uint2*)(Agg + row0 * NH);
  for (int i = tid; i < 1024; i += 256) ((float4*)Hsf)[i] = u2f4(A8[i]);
  __syncthreads();

  int c = tid & 63;
  int rg = tid >> 6;
  float acc[8];
#pragma unroll
  for (int r = 0; r < 8; ++r) acc[r] = 0.f;

  const float4* Hs4 = (const float4*)Hsf;
  for (int kk = 0; kk < 32; ++kk) {
    float4 hv[8];
#pragma unroll
    for (int r = 0; r < 8; ++r) hv[r] = Hs4[(rg + 4 * r) * 32 + kk];
#pragma unroll
    for (int j = 0; j < 4; ++j) {
      float wv = Wsf[(4 * kk + j) * NC + c];
#pragma unroll
      for (int r = 0; r < 8; ++r) {
        float s = (j == 0) ? hv[r].x : (j == 1) ? hv[r].y : (j == 2) ? hv[r].z : hv[r].w;
        acc[r] = fmaf(s, wv, acc[r]);
      }
    }
  }
  if (c < NC) {
    float bc = b10[c];
#pragma unroll
    for (int r = 0; r < 8; ++r)
      S[(row0 + rg + 4 * r) * NC + c] = fmaxf(acc[r] + bc, 0.f);
  }
}

// ---------------- log_softmax over 40 logits per node ----------------
__global__ __launch_bounds__(256) void lsm_kernel(const float* __restrict__ S,
                                                  float* __restrict__ out) {
  int node = blockIdx.x * 4 + (threadIdx.x >> 6);
  int lane = threadIdx.x & 63;
  if (node >= NN) return;
  float v = (lane < NC) ? S[(size_t)node * NC + lane] : -INFINITY;
  float mx = v;
#pragma unroll
  for (int off = 32; off; off >>= 1) mx = fmaxf(mx, __shfl_xor(mx, off));
  float ex = (lane < NC) ? expf(v - mx) : 0.f;
  float ss = ex;
#pragma unroll
  for (int off = 32; off; off >>= 1) ss += __shfl_xor(ss, off);
  if (lane < NC) out[(size_t)node * NC + lane] = v - mx - logf(ss);
}

extern "C" void kernel_launch(void* const* d_in, const int* in_sizes, int n_in,
                              void* d_out, int out_size, void* d_ws, size_t ws_size,
                              hipStream_t stream) {
  const float* x   = (const float*)d_in[0];
  const int*   src = (const int*)d_in[1];
  const int*   dst = (const int*)d_in[2];
  const float* ew  = (const float*)d_in[3];
  const float* W1  = (const float*)d_in[4];
  const float* Wh  = (const float*)d_in[5];
  const float* W10 = (const float*)d_in[6];
  const float* b1  = (const float*)d_in[7];
  const float* bh  = (const float*)d_in[8];
  const float* b10 = (const float*)d_in[9];
  float* out = (float*)d_out;

  // workspace layout (256B-aligned chunks), ~100 MB
  char* p = (char*)d_ws;
  int*   rp    = (int*)p;            p += (((size_t)(NN + 1) * 4 + 255) / 256) * 256;
  int*   roff  = (int*)p;            p += (((size_t)NN * 4 + 255) / 256) * 256;
  int*   bsum  = (int*)p;            p += 256 * 4;
  int*   boff  = (int*)p;            p += 256 * 4;
  u64*   em    = (u64*)p;            p += (size_t)NE * 8;
  unsigned short* hA   = (unsigned short*)p; p += (size_t)NN * NH * 2;
  unsigned short* hB   = (unsigned short*)p; p += (size_t)NN * NH * 2;  // also x-bf16
  unsigned short* aggb = (unsigned short*)p; p += (size_t)NN * NH * 2;
  float* sup40 = (float*)p;          p += (size_t)NN * NC * 4;
  unsigned short* WT   = (unsigned short*)p; p += (size_t)9 * NH * NH * 2;

  // ---- build CSR ----
  hipMemsetAsync(roff, 0, (size_t)NN * 4, stream);
  hist_kernel<<<(NE + 255) / 256, 256, 0, stream>>>(dst, roff, NE);
  scan1_kernel<<<NB_SCAN, 1024, 0, stream>>>(roff, rp, bsum, NN);
  scan2_kernel<<<1, 128, 0, stream>>>(bsum, boff, NB_SCAN);
  scan3_kernel<<<(NN + 255) / 256, 256, 0, stream>>>(rp, roff, boff, NN, NB_SCAN);
  scatter_kernel<<<(NE + 255) / 256, 256, 0, stream>>>(src, dst, ew, roff, em, NE);

  // ---- prep converts ----
  xconv_kernel<<<(NN * NH / 4 + 255) / 256, 256, 0, stream>>>(x, hB, NN * NH / 4);
  wconv_kernel<<<(9 * 16384 + 255) / 256, 256, 0, stream>>>(W1, Wh, WT);

  int layer_grid = (NN + 63) / 64;

  // ---- layer 1: hA = relu((A*x)W1 + b1) ----
  layer_kernel<<<layer_grid, 256, 0, stream>>>(hB, rp, em, WT, b1, hA, 0);

  // ---- 8 hidden residual layers (ping-pong hA/hB) ----
  unsigned short* cur = hA;
  unsigned short* nxt = hB;
  for (int i = 0; i < 8; ++i) {
    layer_kernel<<<layer_grid, 256, 0, stream>>>(
        cur, rp, em, WT + (size_t)(i + 1) * NH * NH, bh + (size_t)i * NH, nxt, 1);
    unsigned short* t = cur; cur = nxt; nxt = t;
  }
  // after 8 swaps, cur == hA

  // ---- final layer + log_softmax ----
  gather_kernel<<<(NN + 15) / 16, 256, 0, stream>>>(cur, rp, em, aggb);
  matmul40_kernel<<<NN / 32, 256, 0, stream>>>(aggb, W10, b10, sup40);
  lsm_kernel<<<(NN + 3) / 4, 256, 0, stream>>>(sup40, out);
}

// Round 12
// 872.379 us; speedup vs baseline: 2.0976x; 1.1885x over previous
//
#include <hip/hip_runtime.h>
#include <math.h>

#define NN 100000
#define NE 800000
#define NH 128
#define NC 40
#define NB_SCAN 98   // ceil(NN/1024)
#define LDH 136      // LDS row stride in shorts (272 B): 16B-aligned, 2-way bank alias only

typedef __attribute__((ext_vector_type(8))) short short8;
typedef __attribute__((ext_vector_type(4))) float floatx4;

__device__ __forceinline__ unsigned short f2b(float f) {
  union { float f; unsigned int u; } x; x.f = f;
  unsigned int r = x.u + 0x7fff + ((x.u >> 16) & 1);  // RTNE
  return (unsigned short)(r >> 16);
}
__device__ __forceinline__ float b2f(unsigned int h16) {  // low 16 bits
  union { unsigned int u; float f; } x; x.u = h16 << 16;
  return x.f;
}
__device__ __forceinline__ unsigned int pk(float lo, float hi) {
  return (unsigned int)f2b(lo) | ((unsigned int)f2b(hi) << 16);
}
__device__ __forceinline__ void acc8(float* a, float w, uint4 v) {
  a[0] = fmaf(w, b2f(v.x & 0xffff), a[0]); a[1] = fmaf(w, b2f(v.x >> 16), a[1]);
  a[2] = fmaf(w, b2f(v.y & 0xffff), a[2]); a[3] = fmaf(w, b2f(v.y >> 16), a[3]);
  a[4] = fmaf(w, b2f(v.z & 0xffff), a[4]); a[5] = fmaf(w, b2f(v.z >> 16), a[5]);
  a[6] = fmaf(w, b2f(v.w & 0xffff), a[6]); a[7] = fmaf(w, b2f(v.w >> 16), a[7]);
}

// compact 4 B edge meta: low 17 bits = src (<2^17), high 15 bits = weight fp32 bits[31:17]
__device__ __forceinline__ void gather_node(const uint4* __restrict__ H4,
                                            const unsigned int* __restrict__ em,
                                            int e0, int e1, int csub, float* a) {
  float c1[8] = {0,0,0,0,0,0,0,0};
  float c2[8] = {0,0,0,0,0,0,0,0};
  float c3[8] = {0,0,0,0,0,0,0,0};
  int e = e0;
  for (; e + 4 <= e1; e += 4) {
    unsigned int m0 = em[e], m1 = em[e + 1], m2 = em[e + 2], m3 = em[e + 3];
    uint4 v0 = H4[(size_t)(m0 & 0x1FFFFu) * 16 + csub];
    uint4 v1 = H4[(size_t)(m1 & 0x1FFFFu) * 16 + csub];
    uint4 v2 = H4[(size_t)(m2 & 0x1FFFFu) * 16 + csub];
    uint4 v3 = H4[(size_t)(m3 & 0x1FFFFu) * 16 + csub];
    acc8(a,  __uint_as_float(m0 & 0xFFFE0000u), v0);
    acc8(c1, __uint_as_float(m1 & 0xFFFE0000u), v1);
    acc8(c2, __uint_as_float(m2 & 0xFFFE0000u), v2);
    acc8(c3, __uint_as_float(m3 & 0xFFFE0000u), v3);
  }
  for (; e < e1; ++e) {
    unsigned int m0 = em[e];
    uint4 v0 = H4[(size_t)(m0 & 0x1FFFFu) * 16 + csub];
    acc8(a, __uint_as_float(m0 & 0xFFFE0000u), v0);
  }
#pragma unroll
  for (int i = 0; i < 8; ++i) a[i] = (a[i] + c1[i]) + (c2[i] + c3[i]);
}

// ---------------- CSR build ----------------
__global__ void hist_kernel(const int* __restrict__ dst, int* __restrict__ cnt, int E) {
  int i = blockIdx.x * 256 + threadIdx.x;
  if (i < E) atomicAdd(&cnt[dst[i]], 1);
}

__global__ __launch_bounds__(1024) void scan1_kernel(const int* __restrict__ cnt,
                                                     int* __restrict__ rp,
                                                     int* __restrict__ bsum, int n) {
  __shared__ int buf[1024];
  int t = threadIdx.x, i = blockIdx.x * 1024 + t;
  int v = (i < n) ? cnt[i] : 0;
  buf[t] = v;
  __syncthreads();
  for (int off = 1; off < 1024; off <<= 1) {
    int x = (t >= off) ? buf[t - off] : 0;
    __syncthreads();
    buf[t] += x;
    __syncthreads();
  }
  if (i < n) rp[i] = buf[t] - v;
  if (t == 1023) bsum[blockIdx.x] = buf[t];
}

__global__ __launch_bounds__(128) void scan2_kernel(const int* __restrict__ bsum,
                                                    int* __restrict__ boff, int nb) {
  __shared__ int buf[128];
  int t = threadIdx.x;
  int v = (t < nb) ? bsum[t] : 0;
  buf[t] = v;
  __syncthreads();
  for (int off = 1; off < 128; off <<= 1) {
    int x = (t >= off) ? buf[t - off] : 0;
    __syncthreads();
    buf[t] += x;
    __syncthreads();
  }
  if (t < nb) boff[t] = buf[t] - v;
  if (t == 127) boff[nb] = buf[t];
}

__global__ void scan3_kernel(int* __restrict__ rp, int* __restrict__ roff,
                             const int* __restrict__ boff, int n, int nb) {
  int i = blockIdx.x * 256 + threadIdx.x;
  if (i < n) {
    int v = rp[i] + boff[i >> 10];
    rp[i] = v;
    roff[i] = v;
  }
  if (i == 0) rp[n] = boff[nb];
}

__global__ void scatter_kernel(const int* __restrict__ src, const int* __restrict__ dst,
                               const float* __restrict__ ew, int* __restrict__ off,
                               unsigned int* __restrict__ em, int E) {
  int i = blockIdx.x * 256 + threadIdx.x;
  if (i < E) {
    int p = atomicAdd(&off[dst[i]], 1);
    em[p] = (__float_as_uint(ew[i]) & 0xFFFE0000u) | (unsigned int)src[i];
  }
}

// ---------------- prep: x fp32 -> bf16 row-major ----------------
__global__ void xconv_kernel(const float* __restrict__ in, unsigned short* __restrict__ out,
                             int n4) {
  int i = blockIdx.x * 256 + threadIdx.x;
  if (i < n4) {
    float4 v = ((const float4*)in)[i];
    uint2 o; o.x = pk(v.x, v.y); o.y = pk(v.z, v.w);
    ((uint2*)out)[i] = o;
  }
}

// 9 dense-128 weights -> bf16, TRANSPOSED: WT[l][n][k] = W_l[k][n]
__global__ void wconv_kernel(const float* __restrict__ W1, const float* __restrict__ Wh,
                             unsigned short* __restrict__ WT) {
  int idx = blockIdx.x * 256 + threadIdx.x;  // 9*16384
  if (idx >= 9 * 16384) return;
  int l = idx >> 14, r = idx & 16383;
  int k = r >> 7, n = r & 127;
  const float* W = (l == 0) ? W1 : (Wh + (size_t)(l - 1) * 16384);
  WT[(size_t)l * 16384 + n * 128 + k] = f2b(W[r]);
}

// W10 fp32 [128][40] -> bf16 transposed+padded: W10b[n][k], n in [0,64), zero for n>=40
__global__ void w10conv_kernel(const float* __restrict__ W10, unsigned short* __restrict__ W10b) {
  int idx = blockIdx.x * 256 + threadIdx.x;  // 64*128
  if (idx >= 64 * 128) return;
  int n = idx >> 7, k = idx & 127;
  W10b[idx] = (n < NC) ? f2b(W10[k * NC + n]) : (unsigned short)0;
}

// ---------------- fused layer: Hout = bf16(relu((A*Hin)*W + b) [+ Hin]) ----------------
// 64 rows/block. Phase 1: gather agg rows into LDS + stage residual rows (coalesced).
// Phase 2: 32x64 MFMA quadrant per wave; B-fragments from global WT (L2-hot).
__global__ __launch_bounds__(256, 4) void layer_kernel(const unsigned short* __restrict__ Hin,
                                                       const int* __restrict__ rp,
                                                       const unsigned int* __restrict__ em,
                                                       const unsigned short* __restrict__ WT,
                                                       const float* __restrict__ bias,
                                                       unsigned short* __restrict__ Hout,
                                                       int residual) {
  __shared__ unsigned short Hs[64 * LDH];
  __shared__ unsigned short Rs[64 * LDH];
  int tid = threadIdx.x;
  int wave = tid >> 6, lane = tid & 63;
  int row0 = blockIdx.x * 64;
  int nsub = lane >> 4;   // 0..3
  int csub = lane & 15;   // 0..15 -> cols csub*8 .. +7
  const uint4* H4 = (const uint4*)Hin;  // 16 uint4 per row

  for (int r = 0; r < 4; ++r) {
    int nl = r * 16 + wave * 4 + nsub;
    int node = row0 + nl;
    int cn = (node < NN) ? node : (NN - 1);
    uint4 rv = H4[(size_t)cn * 16 + csub];          // residual stage (coalesced)
    *(uint4*)(Rs + nl * LDH + csub * 8) = rv;
    float a[8] = {0,0,0,0,0,0,0,0};
    if (node < NN) gather_node(H4, em, rp[node], rp[node + 1], csub, a);
    uint4 o;
    o.x = pk(a[0], a[1]);
    o.y = pk(a[2], a[3]);
    o.z = pk(a[4], a[5]);
    o.w = pk(a[6], a[7]);
    *(uint4*)(Hs + nl * LDH + csub * 8) = o;
  }
  __syncthreads();

  int m = lane & 15;
  int quad = lane >> 4;
  int wr0 = (wave >> 1) * 32;   // 2 m-tiles per wave
  int wc0 = (wave & 1) * 64;    // 4 n-tiles per wave

  floatx4 acc[2][4];
#pragma unroll
  for (int mt = 0; mt < 2; ++mt)
#pragma unroll
    for (int nt = 0; nt < 4; ++nt) acc[mt][nt] = (floatx4){0.f, 0.f, 0.f, 0.f};

#pragma unroll
  for (int ks = 0; ks < 4; ++ks) {
    short8 af[2], bf[4];
#pragma unroll
    for (int mt = 0; mt < 2; ++mt)
      af[mt] = *(const short8*)(Hs + (wr0 + mt * 16 + m) * LDH + quad * 8 + ks * 32);
#pragma unroll
    for (int nt = 0; nt < 4; ++nt)
      bf[nt] = *(const short8*)(WT + (size_t)(wc0 + nt * 16 + m) * 128 + quad * 8 + ks * 32);
#pragma unroll
    for (int mt = 0; mt < 2; ++mt)
#pragma unroll
      for (int nt = 0; nt < 4; ++nt)
        acc[mt][nt] = __builtin_amdgcn_mfma_f32_16x16x32_bf16(af[mt], bf[nt], acc[mt][nt], 0, 0, 0);
  }

  // D: row = quad*4+reg (within 16-tile), col = wc0 + nt*16 + m
#pragma unroll
  for (int nt = 0; nt < 4; ++nt) {
    int col = wc0 + nt * 16 + m;
    float bcol = bias[col];
#pragma unroll
    for (int mt = 0; mt < 2; ++mt) {
#pragma unroll
      for (int reg = 0; reg < 4; ++reg) {
        int lr = wr0 + mt * 16 + quad * 4 + reg;   // local row
        int gr = row0 + lr;
        if (gr < NN) {
          float v = fmaxf(acc[mt][nt][reg] + bcol, 0.f);
          if (residual) v += b2f(Rs[lr * LDH + col]);
          Hout[(size_t)gr * 128 + col] = f2b(v);
        }
      }
    }
  }
}

// ---------------- fused final: out = log_softmax(relu((A*Hin)*W10 + b10)) ----------------
// Phase 1: gather 64 agg rows into LDS. Phase 2: each wave does 16 rows x 64 cols MFMA
// (cols 40..63 are zero-padded W10b), then per-row log-softmax via 16-lane shuffles.
__global__ __launch_bounds__(256, 4) void final_kernel(const unsigned short* __restrict__ Hin,
                                                       const int* __restrict__ rp,
                                                       const unsigned int* __restrict__ em,
                                                       const unsigned short* __restrict__ W10b,
                                                       const float* __restrict__ b10,
                                                       float* __restrict__ out) {
  __shared__ unsigned short Hs[64 * LDH];
  int tid = threadIdx.x;
  int wave = tid >> 6, lane = tid & 63;
  int row0 = blockIdx.x * 64;
  int nsub = lane >> 4;
  int csub = lane & 15;
  const uint4* H4 = (const uint4*)Hin;

  for (int r = 0; r < 4; ++r) {
    int nl = r * 16 + wave * 4 + nsub;
    int node = row0 + nl;
    float a[8] = {0,0,0,0,0,0,0,0};
    if (node < NN) gather_node(H4, em, rp[node], rp[node + 1], csub, a);
    uint4 o;
    o.x = pk(a[0], a[1]);
    o.y = pk(a[2], a[3]);
    o.z = pk(a[4], a[5]);
    o.w = pk(a[6], a[7]);
    *(uint4*)(Hs + nl * LDH + csub * 8) = o;
  }
  __syncthreads();

  int m = lane & 15;
  int quad = lane >> 4;

  floatx4 acc[4];
#pragma unroll
  for (int nt = 0; nt < 4; ++nt) acc[nt] = (floatx4){0.f, 0.f, 0.f, 0.f};

#pragma unroll
  for (int ks = 0; ks < 4; ++ks) {
    short8 af = *(const short8*)(Hs + (wave * 16 + m) * LDH + quad * 8 + ks * 32);
#pragma unroll
    for (int nt = 0; nt < 4; ++nt) {
      short8 bf = *(const short8*)(W10b + (size_t)(nt * 16 + m) * 128 + quad * 8 + ks * 32);
      acc[nt] = __builtin_amdgcn_mfma_f32_16x16x32_bf16(af, bf, acc[nt], 0, 0, 0);
    }
  }

  // D: row = wave*16 + quad*4 + reg, col = nt*16 + m. Valid cols < 40.
  float b0 = b10[m];
  float b1 = b10[16 + m];
  float b2v = (m < 8) ? b10[32 + m] : 0.f;
#pragma unroll
  for (int reg = 0; reg < 4; ++reg) {
    int gr = row0 + wave * 16 + quad * 4 + reg;
    float l0 = fmaxf(acc[0][reg] + b0, 0.f);
    float l1 = fmaxf(acc[1][reg] + b1, 0.f);
    float l2 = (m < 8) ? fmaxf(acc[2][reg] + b2v, 0.f) : -INFINITY;
    float mx = fmaxf(fmaxf(l0, l1), l2);
#pragma unroll
    for (int msk = 1; msk < 16; msk <<= 1) mx = fmaxf(mx, __shfl_xor(mx, msk));
    float ss = expf(l0 - mx) + expf(l1 - mx) + ((m < 8) ? expf(l2 - mx) : 0.f);
#pragma unroll
    for (int msk = 1; msk < 16; msk <<= 1) ss += __shfl_xor(ss, msk);
    float lse = mx + logf(ss);
    if (gr < NN) {
      out[(size_t)gr * NC + m] = l0 - lse;
      out[(size_t)gr * NC + 16 + m] = l1 - lse;
      if (m < 8) out[(size_t)gr * NC + 32 + m] = l2 - lse;
    }
  }
}

extern "C" void kernel_launch(void* const* d_in, const int* in_sizes, int n_in,
                              void* d_out, int out_size, void* d_ws, size_t ws_size,
                              hipStream_t stream) {
  const float* x   = (const float*)d_in[0];
  const int*   src = (const int*)d_in[1];
  const int*   dst = (const int*)d_in[2];
  const float* ew  = (const float*)d_in[3];
  const float* W1  = (const float*)d_in[4];
  const float* Wh  = (const float*)d_in[5];
  const float* W10 = (const float*)d_in[6];
  const float* b1  = (const float*)d_in[7];
  const float* bh  = (const float*)d_in[8];
  const float* b10 = (const float*)d_in[9];
  float* out = (float*)d_out;

  // workspace layout (256B-aligned chunks), ~60 MB
  char* p = (char*)d_ws;
  int*   rp    = (int*)p;            p += (((size_t)(NN + 1) * 4 + 255) / 256) * 256;
  int*   roff  = (int*)p;            p += (((size_t)NN * 4 + 255) / 256) * 256;
  int*   bsum  = (int*)p;            p += 256 * 4;
  int*   boff  = (int*)p;            p += 256 * 4;
  unsigned int* em = (unsigned int*)p; p += (size_t)NE * 4;
  unsigned short* hA   = (unsigned short*)p; p += (size_t)NN * NH * 2;
  unsigned short* hB   = (unsigned short*)p; p += (size_t)NN * NH * 2;  // also x-bf16
  unsigned short* WT   = (unsigned short*)p; p += (size_t)9 * NH * NH * 2;
  unsigned short* W10b = (unsigned short*)p; p += (size_t)64 * NH * 2;

  // ---- build CSR ----
  hipMemsetAsync(roff, 0, (size_t)NN * 4, stream);
  hist_kernel<<<(NE + 255) / 256, 256, 0, stream>>>(dst, roff, NE);
  scan1_kernel<<<NB_SCAN, 1024, 0, stream>>>(roff, rp, bsum, NN);
  scan2_kernel<<<1, 128, 0, stream>>>(bsum, boff, NB_SCAN);
  scan3_kernel<<<(NN + 255) / 256, 256, 0, stream>>>(rp, roff, boff, NN, NB_SCAN);
  scatter_kernel<<<(NE + 255) / 256, 256, 0, stream>>>(src, dst, ew, roff, em, NE);

  // ---- prep converts ----
  xconv_kernel<<<(NN * NH / 4 + 255) / 256, 256, 0, stream>>>(x, hB, NN * NH / 4);
  wconv_kernel<<<(9 * 16384 + 255) / 256, 256, 0, stream>>>(W1, Wh, WT);
  w10conv_kernel<<<(64 * 128 + 255) / 256, 256, 0, stream>>>(W10, W10b);

  int layer_grid = (NN + 63) / 64;

  // ---- layer 1: hA = relu((A*x)W1 + b1) ----
  layer_kernel<<<layer_grid, 256, 0, stream>>>(hB, rp, em, WT, b1, hA, 0);

  // ---- 8 hidden residual layers (ping-pong hA/hB) ----
  unsigned short* cur = hA;
  unsigned short* nxt = hB;
  for (int i = 0; i < 8; ++i) {
    layer_kernel<<<layer_grid, 256, 0, stream>>>(
        cur, rp, em, WT + (size_t)(i + 1) * NH * NH, bh + (size_t)i * NH, nxt, 1);
    unsigned short* t = cur; cur = nxt; nxt = t;
  }
  // after 8 swaps, cur == hA

  // ---- fused final layer + log_softmax ----
  final_kernel<<<layer_grid, 256, 0, stream>>>(cur, rp, em, W10b, b10, out);
}